// Round 2
// baseline (10222.508 us; speedup 1.0000x reference)
//
#include <hip/hip_runtime.h>
#include <hip/hip_fp16.h>

// Persistent clustered LSTM scan for MI355X — round 2.
// 4 clusters x 16 batch rows; 32 WGs/cluster; WG = 256 thr (4 waves), 1 WG/CU.
// Wave w == gate w (i,f,g,o). Weights persistent in VGPRs (f16, 128 regs/lane).
// Sync per step: per-producer release flag stores + 32-lane relaxed poll +
// acquire fence (no contended RMW). h' exchanged as f16 in A-fragment layout,
// consumed by direct global->reg loads (no LDS round-trip). ys stores off the
// critical path (after flag raise).

typedef _Float16 f16x8 __attribute__((ext_vector_type(8)));
typedef _Float16 f16x4 __attribute__((ext_vector_type(4)));
typedef float    f32x4 __attribute__((ext_vector_type(4)));

__device__ __forceinline__ float sigmoid_f(float v) {
    return 1.f / (1.f + __expf(-v));
}
__device__ __forceinline__ float tanh_f(float v) {
    v = fminf(15.f, fmaxf(-15.f, v));
    const float e = __expf(2.f * v);
    return (e - 1.f) / (e + 1.f);
}

__global__ __launch_bounds__(256, 1)
void lstm_persistent(const float* __restrict__ x,
                     const float* __restrict__ c0,
                     const float* __restrict__ h0,
                     const float* __restrict__ Wi,
                     const float* __restrict__ Wh,
                     const float* __restrict__ bias,
                     float* __restrict__ out,
                     unsigned* __restrict__ flags,   // 4 clusters x 32 wg
                     _Float16* __restrict__ exch)    // 2 x 64 x 512 f16
{
    const int bid  = blockIdx.x;
    const int cl   = (bid & 7) >> 1;                 // 0..3 (cluster on 2 XCDs)
    const int wg   = ((bid >> 3) << 1) | (bid & 1);  // 0..31 within cluster
    const int tid  = threadIdx.x;
    const int w    = tid >> 6;                       // wave == gate
    const int lane = tid & 63;
    const int q    = lane >> 4;
    const int n16  = lane & 15;

    const int gb0  = cl * 16;
    const int col0 = wg * 16;

    __shared__ _Float16 Axl[16 * 512];               // 16 KB: x_t, rotate-8/row
    __shared__ float    glds[4][16][20];             // stride 20: <=2-way (free)

    unsigned* myflags = flags + cl * 32;
    _Float16* exbuf0 = exch;
    _Float16* exbuf1 = exch + 64 * 512;

    // ---------------- B preload: persistent weight fragments -------------------
    // B[k][n]: lane n = lane&15, k = quad*8 + j per K=32 step.
    f16x8 Breg[32];
    {
        const int cg = w * 512 + col0 + n16;
#pragma unroll
        for (int kk = 0; kk < 32; ++kk) {
            const int kbase = kk * 32 + q * 8;
            f16x8 v;
#pragma unroll
            for (int j = 0; j < 8; ++j) {
                const int k = kbase + j;
                const float f = (k < 512) ? Wi[(size_t)k * 2048 + cg]
                                          : Wh[(size_t)(k - 512) * 2048 + cg];
                v[j] = (_Float16)f;
            }
            Breg[kk] = v;
        }
    }

    // ---------------- elementwise state: thread -> (batch eb, col ej) ----------
    const int eb = tid >> 4;
    const int ej = tid & 15;
    const float bi_i = bias[0 * 512 + col0 + ej];
    const float bi_f = bias[1 * 512 + col0 + ej];
    const float bi_g = bias[2 * 512 + col0 + ej];
    const float bi_o = bias[3 * 512 + col0 + ej];
    float cst = c0[(size_t)(gb0 + eb) * 512 + col0 + ej];

    // ---------------- pre-loop: load + stage x_0 -------------------------------
    float4 xr[8];
#pragma unroll
    for (int cc = 0; cc < 8; ++cc) {
        const int chunk = tid + cc * 256;
        const int b  = chunk >> 7;
        const int k4 = chunk & 127;
        xr[cc] = *(const float4*)&x[(size_t)(gb0 + b) * 1024 * 512 + k4 * 4];
    }
#pragma unroll
    for (int cc = 0; cc < 8; ++cc) {
        const int chunk = tid + cc * 256;
        const int b = chunk >> 7;
        const int k = (chunk & 127) * 4;
        f16x4 v;
        v[0] = (_Float16)xr[cc].x; v[1] = (_Float16)xr[cc].y;
        v[2] = (_Float16)xr[cc].z; v[3] = (_Float16)xr[cc].w;
        *(f16x4*)&Axl[b * 512 + ((k + 8 * b) & 511)] = v;
    }
    __syncthreads();

    for (int t = 0; t < 1024; ++t) {
        // ---- issue x_{t+1} prefetch: a full step of slack ----------------------
        if (t < 1023) {
#pragma unroll
            for (int cc = 0; cc < 8; ++cc) {
                const int chunk = tid + cc * 256;
                const int b  = chunk >> 7;
                const int k4 = chunk & 127;
                xr[cc] = *(const float4*)&x[((size_t)(gb0 + b) * 1024 + (t + 1)) * 512 + k4 * 4];
            }
        }

        // ---- wait for h_t: 32-lane parallel relaxed poll + acquire fence -------
        if (t > 0) {
            if (lane < 32) {
                const unsigned* f = myflags + lane;
                const unsigned tgt = (unsigned)t;
                int guard = 1 << 18;                 // deadlock safety valve
                while (__hip_atomic_load(f, __ATOMIC_RELAXED,
                                         __HIP_MEMORY_SCOPE_AGENT) < tgt) {
                    __builtin_amdgcn_s_sleep(1);
                    if (--guard == 0) break;
                }
            }
            __builtin_amdgcn_fence(__ATOMIC_ACQUIRE, "agent");
        }

        // ---- h_t fragments: direct global -> registers -------------------------
        float4 hload[16];
        if (t == 0) {
            const float* hrow = h0 + (size_t)(gb0 + n16) * 512;
#pragma unroll
            for (int kk = 0; kk < 16; ++kk) {
                const int k0 = kk * 32 + q * 8;
                const float4 a0 = *(const float4*)&hrow[k0];
                const float4 a1 = *(const float4*)&hrow[k0 + 4];
                union { f16x8 h; float4 f; } u;
                u.h[0]=(_Float16)a0.x; u.h[1]=(_Float16)a0.y;
                u.h[2]=(_Float16)a0.z; u.h[3]=(_Float16)a0.w;
                u.h[4]=(_Float16)a1.x; u.h[5]=(_Float16)a1.y;
                u.h[6]=(_Float16)a1.z; u.h[7]=(_Float16)a1.w;
                hload[kk] = u.f;
            }
        } else {
            const _Float16* hrow = ((t & 1) ? exbuf1 : exbuf0) + (size_t)(gb0 + n16) * 512;
#pragma unroll
            for (int kk = 0; kk < 16; ++kk)
                hload[kk] = *(const float4*)&hrow[kk * 32 + q * 8];
        }

        // ---- GEMM: x-half first (hides h-load latency), then h-half ------------
        f32x4 acc0 = {0.f, 0.f, 0.f, 0.f}, acc1 = {0.f, 0.f, 0.f, 0.f};
        {
            const int m   = n16;
            const int rot = 8 * m;
#pragma unroll
            for (int kk = 0; kk < 16; kk += 2) {
                const int k0 = kk * 32 + q * 8;
                const f16x8 a0 = *(const f16x8*)&Axl[m * 512 + ((k0      + rot) & 511)];
                const f16x8 a1 = *(const f16x8*)&Axl[m * 512 + ((k0 + 32 + rot) & 511)];
                acc0 = __builtin_amdgcn_mfma_f32_16x16x32_f16(a0, Breg[kk],     acc0, 0, 0, 0);
                acc1 = __builtin_amdgcn_mfma_f32_16x16x32_f16(a1, Breg[kk + 1], acc1, 0, 0, 0);
            }
#pragma unroll
            for (int kk = 0; kk < 16; kk += 2) {
                union { float4 f; f16x8 h; } u0, u1;
                u0.f = hload[kk]; u1.f = hload[kk + 1];
                acc0 = __builtin_amdgcn_mfma_f32_16x16x32_f16(u0.h, Breg[16 + kk],     acc0, 0, 0, 0);
                acc1 = __builtin_amdgcn_mfma_f32_16x16x32_f16(u1.h, Breg[16 + kk + 1], acc1, 0, 0, 0);
            }
        }
        // C layout: col = lane&15, row = quad*4 + reg
#pragma unroll
        for (int r = 0; r < 4; ++r)
            glds[w][q * 4 + r][n16] = acc0[r] + acc1[r];
        __syncthreads();                              // #1: gates ready, Axl free

        // ---- elementwise gates + state update ----------------------------------
        const float yi = glds[0][eb][ej] + bi_i;
        const float yf = glds[1][eb][ej] + bi_f;
        const float yg = glds[2][eb][ej] + bi_g;
        const float yo = glds[3][eb][ej] + bi_o;
        cst = sigmoid_f(yf) * cst + sigmoid_f(yi) * tanh_f(yg);
        const float hn = sigmoid_f(yo) * tanh_f(cst);

        if (t < 1023) {
            // ---- publish h' as f16 (pack pairs via shfl, 4B agent stores) ------
            const _Float16 hf = (_Float16)hn;
            unsigned ub;
            { union { _Float16 h; unsigned short s; } c; c.h = hf; ub = c.s; }
            const unsigned pb = __shfl_xor((int)ub, 1);
            if ((ej & 1) == 0) {
                _Float16* dstbuf = ((t & 1) ? exbuf0 : exbuf1);   // buf[(t+1)&1]
                unsigned* dst = (unsigned*)(dstbuf + (size_t)(gb0 + eb) * 512 + col0 + ej);
                __hip_atomic_store(dst, ub | (pb << 16),
                                   __ATOMIC_RELAXED, __HIP_MEMORY_SCOPE_AGENT);
            }
            // ---- stage x_{t+1} from prefetch regs ------------------------------
#pragma unroll
            for (int cc = 0; cc < 8; ++cc) {
                const int chunk = tid + cc * 256;
                const int b = chunk >> 7;
                const int k = (chunk & 127) * 4;
                f16x4 v;
                v[0] = (_Float16)xr[cc].x; v[1] = (_Float16)xr[cc].y;
                v[2] = (_Float16)xr[cc].z; v[3] = (_Float16)xr[cc].w;
                *(f16x4*)&Axl[b * 512 + ((k + 8 * b) & 511)] = v;
            }
        }
        __syncthreads();                              // #2: drain h' stores + Axl

        if (t < 1023 && tid == 0) {
            __hip_atomic_store(myflags + wg, (unsigned)(t + 1),
                               __ATOMIC_RELEASE, __HIP_MEMORY_SCOPE_AGENT);
        }

        // ---- outputs: off the critical path ------------------------------------
        out[65536 + ((size_t)(gb0 + eb) * 1024 + t) * 512 + col0 + ej] = hn;
        if (t == 1023) {
            out[(size_t)(gb0 + eb) * 512 + col0 + ej]         = cst;  // cT
            out[32768 + (size_t)(gb0 + eb) * 512 + col0 + ej] = hn;   // hT
        }
    }
}

extern "C" void kernel_launch(void* const* d_in, const int* in_sizes, int n_in,
                              void* d_out, int out_size, void* d_ws, size_t ws_size,
                              hipStream_t stream) {
    const float* x  = (const float*)d_in[0];
    const float* c0 = (const float*)d_in[1];
    const float* h0 = (const float*)d_in[2];
    const float* Wi = (const float*)d_in[3];
    const float* Wh = (const float*)d_in[4];
    const float* b  = (const float*)d_in[5];
    float* out = (float*)d_out;

    // ws: [0,1024) flags (4 clusters x 32 x u32, zeroed), then 2 x 64*512 f16
    hipMemsetAsync(d_ws, 0, 1024, stream);
    unsigned* flags = (unsigned*)d_ws;
    _Float16* exch  = (_Float16*)((char*)d_ws + 1024);

    hipLaunchKernelGGL(lstm_persistent, dim3(128), dim3(256), 0, stream,
                       x, c0, h0, Wi, Wh, b, out, flags, exch);
}